// Round 1
// baseline (691.064 us; speedup 1.0000x reference)
//
#include <hip/hip_runtime.h>

#define AREA 4096

// ---------------- pointwise channel projection -------------------------
// out[n, o, a] = act( sum_c in[n, c, a] * Wm[o, c] + bias[o] ) (+ res)
template<bool GELU, bool RES>
__global__ __launch_bounds__(256) void proj_kernel(
    const float* __restrict__ in, const float* __restrict__ Wm,
    const float* __restrict__ bias, float* __restrict__ out,
    const float* __restrict__ res,
    int Cin, long in_stride, long out_stride)
{
    const int TO = 16, CH = 8;
    __shared__ float wt[CH][TO];
    const int tid = threadIdx.x;
    const int a = blockIdx.x * 256 + tid;
    const int o0 = blockIdx.y * TO;
    const int n = blockIdx.z;
    const float* inp = in + (long)n * in_stride;
    float acc[TO];
#pragma unroll
    for (int i = 0; i < TO; ++i) acc[i] = 0.f;

    for (int c0 = 0; c0 < Cin; c0 += CH) {
        __syncthreads();
        if (tid < CH * TO) {
            int cc = tid >> 4;
            int oo = tid & 15;
            wt[cc][oo] = Wm[(long)(o0 + oo) * Cin + (c0 + cc)];
        }
        __syncthreads();
#pragma unroll
        for (int cc = 0; cc < CH; ++cc) {
            float xv = inp[(long)(c0 + cc) * AREA + a];
#pragma unroll
            for (int oo = 0; oo < TO; ++oo)
                acc[oo] = fmaf(wt[cc][oo], xv, acc[oo]);
        }
    }
    const long obase = (long)n * out_stride;
#pragma unroll
    for (int oo = 0; oo < TO; ++oo) {
        float vr = acc[oo] + bias[o0 + oo];
        if (GELU) vr = 0.5f * vr * (1.f + erff(vr * 0.70710678118654752f));
        if (RES) vr += res[obase + (long)(o0 + oo) * AREA + a];
        out[obase + (long)(o0 + oo) * AREA + a] = vr;
    }
}

// ---------------- deformable attention ---------------------------------
// qp: (B, 288, A)   kv: (B*CLIP, 576, A)   offs: (B, 432, A)   o: (B, 288, A)
__global__ __launch_bounds__(256) void deform_attn_kernel(
    const float* __restrict__ qp, const float* __restrict__ kv,
    const float* __restrict__ offs, float* __restrict__ o)
{
    const int t = blockIdx.x * 256 + threadIdx.x;   // B*12*A threads
    const int a = t & (AREA - 1);
    const int g = (t >> 12) % 12;
    const int b = t / (12 * AREA);
    const int py = a >> 6;
    const int px = a & 63;
    const float scale = 0.20412414523193150818f;    // 1/sqrt(24)

    float qv[24];
#pragma unroll
    for (int d = 0; d < 24; ++d)
        qv[d] = qp[((long)b * 288 + g * 24 + d) * AREA + a] * scale;

    float m = -1e30f, l = 0.f;
    float outv[24];
#pragma unroll
    for (int d = 0; d < 24; ++d) outv[d] = 0.f;

    for (int clip = 0; clip < 2; ++clip) {
        const float* kbase = kv + ((long)(b * 2 + clip) * 576 + g * 24) * AREA;
        const float* vbase = kbase + 288L * AREA;
        const float* obase = offs + ((long)b * 432 + (clip * 12 + g) * 18) * AREA;
        for (int k = 0; k < 9; ++k) {
            float oy = obase[(long)(2 * k) * AREA + a];
            float ox = obase[(long)(2 * k + 1) * AREA + a];
            int ky = k / 3, kx = k - ky * 3;
            float ys = (float)(py + ky - 1) + oy;
            float xs = (float)(px + kx - 1) + ox;
            float y0f = floorf(ys), x0f = floorf(xs);
            float dy = ys - y0f, dx = xs - x0f;
            float wy[2] = {1.f - dy, dy};
            float wx[2] = {1.f - dx, dx};
            int   idx4[4];
            float w4[4];
#pragma unroll
            for (int cy = 0; cy < 2; ++cy) {
                float yc = y0f + (float)cy;
                bool vy = (yc >= 0.f) && (yc <= 63.f);
                int yi = (int)fminf(fmaxf(yc, 0.f), 63.f);
#pragma unroll
                for (int cx = 0; cx < 2; ++cx) {
                    float xc = x0f + (float)cx;
                    bool vx = (xc >= 0.f) && (xc <= 63.f);
                    int xi = (int)fminf(fmaxf(xc, 0.f), 63.f);
                    w4[cy * 2 + cx] = wy[cy] * wx[cx] * ((vy && vx) ? 1.f : 0.f);
                    idx4[cy * 2 + cx] = yi * 64 + xi;
                }
            }
            // logit = q . k_sampled
            float s = 0.f;
#pragma unroll
            for (int d = 0; d < 24; ++d) {
                const float* kc = kbase + (long)d * AREA;
                float ksamp = w4[0] * kc[idx4[0]] + w4[1] * kc[idx4[1]]
                            + w4[2] * kc[idx4[2]] + w4[3] * kc[idx4[3]];
                s = fmaf(qv[d], ksamp, s);
            }
            // online softmax update + V accumulate
            float mn = fmaxf(m, s);
            float corr = __expf(m - mn);
            float p = __expf(s - mn);
            l = l * corr + p;
#pragma unroll
            for (int d = 0; d < 24; ++d) {
                const float* vc = vbase + (long)d * AREA;
                float vsamp = w4[0] * vc[idx4[0]] + w4[1] * vc[idx4[1]]
                            + w4[2] * vc[idx4[2]] + w4[3] * vc[idx4[3]];
                outv[d] = fmaf(outv[d], corr, p * vsamp);
            }
            m = mn;
        }
    }
    float inv = 1.f / l;
#pragma unroll
    for (int d = 0; d < 24; ++d)
        o[((long)b * 288 + g * 24 + d) * AREA + a] = outv[d] * inv;
}

extern "C" void kernel_launch(void* const* d_in, const int* in_sizes, int n_in,
                              void* d_out, int out_size, void* d_ws, size_t ws_size,
                              hipStream_t stream) {
    const float* q      = (const float*)d_in[0];
    const float* k      = (const float*)d_in[1];
    const float* v      = (const float*)d_in[2];
    const float* offset = (const float*)d_in[3];
    const float* Wq     = (const float*)d_in[4];
    const float* bq     = (const float*)d_in[5];
    const float* Wk     = (const float*)d_in[6];
    const float* bk     = (const float*)d_in[7];
    const float* Wv     = (const float*)d_in[8];
    const float* bv     = (const float*)d_in[9];
    const float* W1     = (const float*)d_in[10];
    const float* b1     = (const float*)d_in[11];
    const float* W2     = (const float*)d_in[12];
    const float* b2     = (const float*)d_in[13];
    float* out = (float*)d_out;
    float* ws  = (float*)d_ws;

    float* qp  = ws;                       // 2*288*4096 = 2,359,296 floats
    float* kvb = ws + 2359296;             // 4*576*4096 = 9,437,184 floats
    float* x1  = kvb;                      // aliases kv after attention (needs 4,718,592)

    dim3 blk(256);
    // q projection: (B=2 imgs of 288xA) -> qp
    proj_kernel<false, false><<<dim3(16, 18, 2), blk, 0, stream>>>(
        q, Wq, bq, qp, nullptr, 288, 288L * AREA, 288L * AREA);
    // k projection -> kv[:, 0:288]
    proj_kernel<false, false><<<dim3(16, 18, 4), blk, 0, stream>>>(
        k, Wk, bk, kvb, nullptr, 288, 288L * AREA, 576L * AREA);
    // v projection -> kv[:, 288:576]
    proj_kernel<false, false><<<dim3(16, 18, 4), blk, 0, stream>>>(
        v, Wv, bv, kvb + 288L * AREA, nullptr, 288, 288L * AREA, 576L * AREA);
    // deformable attention -> out (this is "o")
    deform_attn_kernel<<<dim3(384), blk, 0, stream>>>(qp, kvb, offset, out);
    // FFN layer 1: out(288) -> x1(576), GELU
    proj_kernel<true, false><<<dim3(16, 36, 2), blk, 0, stream>>>(
        out, W1, b1, x1, nullptr, 288, 288L * AREA, 576L * AREA);
    // FFN layer 2: x1(576) -> out(288), + residual o (in-place safe: same element)
    proj_kernel<false, true><<<dim3(16, 18, 2), blk, 0, stream>>>(
        x1, W2, b2, out, out, 576, 576L * AREA, 288L * AREA);
}